// Round 6
// baseline (351.813 us; speedup 1.0000x reference)
//
#include <hip/hip_runtime.h>
#include <stdint.h>

// HOPELoRALayer — B=8, S=4096, D=1024, R_TOT=104. fp32 I/O; bf16 MFMA GEMM.
// Reductions:
//   gate_scale = mean(softmax over 3) == 1/3 exactly -> gate net dead code.
//   out = X @ (base_w + (1/3) pu@diag(1+mem)@pd)^T + base_b
// mem==0 (fresh state) -> batch-independent W0; general case kept via
// per-batch flag + Weff (computed only if mem[b]!=0).
//
// R9 = R7 fusion with the counted-wait bug fixed (R8's failure):
//   - prologue wait is vmcnt(2): outstanding at that point = 4 (B0's 2 +
//     B1's 2 global_load_lds; the A register-loads are already drained by
//     A_WRITE's implicit dependence waits). vmcnt(2) drains B0 exactly.
//     R8's vmcnt(4) was a no-op -> tile-0 B read before landing -> absmax 1.2.
//   - ph1 issues STAGE_B(kt+2) BEFORE A_WRITE(kt+2) so the implicit wait for
//     s0..s3 is vmcnt(2) (B(kt+2) stays in flight), not a full drain.
// R7 change: convert_x kernel DELETED — fp32->bf16 conversion fused into the
// GEMM's A-staging (saves 192 MB of HBM traffic + one serialized launch).
//   A path: ph0 issues 4x global_load_dwordx4 of fp32 x (T14 issue-early);
//           ph1 converts (RNE) + 2x ds_write_b128 into the swizzled slot of
//           buf[(kt+2)&3]. Write-side XOR == read-side XOR (involution).
//   B path: unchanged global_load_lds with pre-swizzled global source.
//   lgkmcnt(0) before each tile-end s_barrier publishes the ds_writes.

typedef unsigned short ushort_t;
typedef unsigned short us8 __attribute__((ext_vector_type(8)));
typedef short short8 __attribute__((ext_vector_type(8)));
typedef float f32x4 __attribute__((ext_vector_type(4)));

__device__ __forceinline__ ushort_t f2b(float f) {  // RNE fp32->bf16
  union { float f; uint32_t i; } v; v.f = f;
  uint32_t lsb = (v.i >> 16) & 1u;
  v.i += 0x7fffu + lsb;
  return (ushort_t)(v.i >> 16);
}

__device__ __forceinline__ void async16(const void* g, void* l) {
  __builtin_amdgcn_global_load_lds(
      (const __attribute__((address_space(1))) void*)g,
      (__attribute__((address_space(3))) void*)l, 16, 0, 0);
}

// ---- merged prep: y==0 -> W0 row; y=1..8 -> flags[b] + Weff row if mem!=0 --
__global__ __launch_bounds__(128) void prep(const float* __restrict__ base_w,
                                            const float* __restrict__ pu_w,
                                            const float* __restrict__ pd_w,
                                            const float* __restrict__ mf,
                                            const float* __restrict__ mm,
                                            const float* __restrict__ ms,
                                            ushort_t* __restrict__ W0,
                                            ushort_t* __restrict__ Weff,
                                            int* __restrict__ flags) {
  const int o = blockIdx.x, y = blockIdx.y, t = threadIdx.x;
  __shared__ float spu[104];
  __shared__ int sflag;
  ushort_t* dst;

  if (y == 0) {
    if (t < 104) spu[t] = pu_w[o * 104 + t] * (1.0f / 3.0f);
    dst = W0 + o * 1024;
    __syncthreads();
  } else {
    const int b = y - 1;
    if (t == 0) sflag = 0;
    __syncthreads();
    float mv = 0.0f;
    if (t < 104) {
      mv = (t < 8) ? mf[b * 8 + t]
         : (t < 40) ? mm[b * 32 + (t - 8)]
                    : ms[b * 64 + (t - 40)];
      if (mv != 0.0f) sflag = 1;
      spu[t] = pu_w[o * 104 + t] * (1.0f + mv) * (1.0f / 3.0f);
    }
    __syncthreads();
    if (o == 0 && t == 0) flags[b] = sflag;
    if (!sflag) return;  // block-uniform
    dst = Weff + ((size_t)b << 20) + o * 1024;
  }

  const int d0 = t * 8;
  float acc[8];
  f32x4 b0 = *(const f32x4*)(base_w + o * 1024 + d0);
  f32x4 b1 = *(const f32x4*)(base_w + o * 1024 + d0 + 4);
#pragma unroll
  for (int j = 0; j < 4; j++) { acc[j] = b0[j]; acc[4 + j] = b1[j]; }
  for (int r = 0; r < 104; r++) {
    f32x4 p0 = *(const f32x4*)(pd_w + r * 1024 + d0);
    f32x4 p1 = *(const f32x4*)(pd_w + r * 1024 + d0 + 4);
    float s = spu[r];
#pragma unroll
    for (int j = 0; j < 4; j++) { acc[j] += s * p0[j]; acc[4 + j] += s * p1[j]; }
  }
  us8 ov;
#pragma unroll
  for (int j = 0; j < 8; j++) ov[j] = f2b(acc[j]);
  *(us8*)(dst + d0) = ov;
}

// ---- main GEMM: out[b, m, n] = sum_k x[b,m,k] * W[n,k] + base_b[n] --------
// 256x256 tile, BK=32. 8 waves (2M x 4N), per-wave 128x64 out = 8x4 frags of
// mfma_f32_16x16x32_bf16. Grid 512 blocks: b = flat&7 (batch==XCD).
// A read directly from fp32 x (reg-staged + in-kernel bf16 convert).
__global__ __launch_bounds__(512, 2) void gemm256(
    const float* __restrict__ x, const float* __restrict__ base_b,
    const ushort_t* __restrict__ W0, const ushort_t* __restrict__ Weff,
    const int* __restrict__ flags, float* __restrict__ out) {
  const int flat = blockIdx.x;
  const int b  = flat & 7;                 // batch == XCD
  const int i  = flat >> 3;                // 0..63
  const int bm = i >> 2;                   // 0..15 (M tile)
  const int bn = i & 3;                    // 0..3  (N tile)

  const ushort_t* W = flags[b] ? (Weff + ((size_t)b << 20)) : W0;

  // 4-deep ring: per buffer A[256][32] (16KiB) + B[256][32] (16KiB) = 32KiB
  __shared__ __align__(16) char lds[4 * 32768];  // 128 KiB

  const int t = threadIdx.x;
  const int w = t >> 6, l = t & 63;
  const int wr = w >> 2, wc = w & 3;       // wave -> (M half, N quarter)
  const int row16 = l & 15, quad = l >> 4;

  // ---- B staging (global_load_lds, source carries the inverse swizzle) ----
  const int srow = w * 16 + (l >> 2);
  const int scol = ((l & 3) ^ ((l >> 3) & 3)) * 8;     // bf16 units
  const ushort_t* gB = W + (((size_t)(bn * 256 + srow)) << 10) + scol;

  // ---- A staging (reg-staged fp32 -> cvt -> swizzled ds_write) ----
  // thread t covers LDS row ar = t>>1, fp32 cols ac..ac+15 (ac = (t&1)*16).
  const int ar = t >> 1;                               // 0..255
  const int ac = (t & 1) * 16;
  const float* gA = x + (((size_t)b * 4096 + bm * 256 + ar) << 10) + ac;
  const int fr_ = (ar >> 1) & 3;                       // row swizzle key
  const int ws0 = (((t & 1) * 2 + 0) ^ fr_) * 16;      // byte slots
  const int ws1 = (((t & 1) * 2 + 1) ^ fr_) * 16;

  // ---- ds_read addressing (applies the same XOR on the k-slot) ----
  const int qsw = (quad ^ ((row16 >> 1) & 3)) * 16;          // byte slot
  const int aoff = (wr * 128 + row16) * 64 + qsw;            // + mi*1024
  const int boff = 16384 + (wc * 64 + row16) * 64 + qsw;     // + ni*1024

#define STAGE_B(kt)                                                       \
  {                                                                       \
    const ushort_t* g_ = gB + (kt) * 32;                                  \
    char* d_ = lds + ((kt) & 3) * 32768 + 16384 + w * 1024;               \
    async16(g_, d_);                                                      \
    async16(g_ + (128 << 10), d_ + 8192);                                 \
  }
#define A_ISSUE(kt2)                                                      \
  {                                                                       \
    const float* p_ = gA + (kt2) * 32;                                    \
    s0 = *(const f32x4*)(p_);      s1 = *(const f32x4*)(p_ + 4);          \
    s2 = *(const f32x4*)(p_ + 8);  s3 = *(const f32x4*)(p_ + 12);         \
  }
#define A_WRITE(kt2)                                                      \
  {                                                                       \
    us8 o0, o1;                                                           \
    _Pragma("unroll")                                                     \
    for (int j_ = 0; j_ < 4; ++j_) {                                      \
      o0[j_] = f2b(s0[j_]); o0[4 + j_] = f2b(s1[j_]);                     \
      o1[j_] = f2b(s2[j_]); o1[4 + j_] = f2b(s3[j_]);                     \
    }                                                                     \
    char* d_ = lds + ((kt2) & 3) * 32768 + ar * 64;                       \
    *(us8*)(d_ + ws0) = o0;                                               \
    *(us8*)(d_ + ws1) = o1;                                               \
  }

  f32x4 acc[8][4] = {};
  f32x4 s0, s1, s2, s3;

  // prologue: A0 cvt+written; A1 cvt+written; B0,B1 issued. Outstanding VM
  // at the wait = 4 (B0:2, B1:2) — A reg-loads already drained by A_WRITE's
  // implicit waits. vmcnt(2) drains exactly B0; B1 stays in flight.
  A_ISSUE(0) A_WRITE(0)
  A_ISSUE(1) STAGE_B(0)
  A_WRITE(1) STAGE_B(1)
  asm volatile("s_waitcnt vmcnt(2) lgkmcnt(0)" ::: "memory");
  __builtin_amdgcn_s_barrier();

  for (int kt = 0; kt < 32; ++kt) {
    const char* cur = lds + (kt & 3) * 32768;

    // ---- phase 0: read af0..3 + bf0..3 | issue A-loads(kt+2) | 16 MFMA ----
    short8 af[4], bf[4];
#pragma unroll
    for (int mi = 0; mi < 4; ++mi)
      af[mi] = *(const short8*)(cur + aoff + mi * 1024);
#pragma unroll
    for (int ni = 0; ni < 4; ++ni)
      bf[ni] = *(const short8*)(cur + boff + ni * 1024);
    if (kt < 30) A_ISSUE(kt + 2)
    __builtin_amdgcn_sched_barrier(0);   // pin reads + A-load issue here
    __builtin_amdgcn_s_barrier();
    __builtin_amdgcn_s_setprio(1);
#pragma unroll
    for (int mi = 0; mi < 4; ++mi)
#pragma unroll
      for (int ni = 0; ni < 4; ++ni)
        acc[mi][ni] = __builtin_amdgcn_mfma_f32_16x16x32_bf16(af[mi], bf[ni],
                                                              acc[mi][ni], 0, 0, 0);
    __builtin_amdgcn_s_setprio(0);

    // ---- phase 1: read af4..7 | stage B(kt+2) THEN cvt+ds_write A(kt+2) |
    //      16 MFMA. B-before-A keeps the implicit s0..s3 wait at vmcnt(2)
    //      (B(kt+2) newest stays in flight) and drains B(kt+1) as a side
    //      effect — the buffer published at this tile's end barrier.
    short8 af2[4];
#pragma unroll
    for (int mi = 0; mi < 4; ++mi)
      af2[mi] = *(const short8*)(cur + aoff + (4 + mi) * 1024);
    if (kt < 30) { STAGE_B(kt + 2) A_WRITE(kt + 2) }
    __builtin_amdgcn_sched_barrier(0);
    __builtin_amdgcn_s_barrier();
    __builtin_amdgcn_s_setprio(1);
#pragma unroll
    for (int mi = 0; mi < 4; ++mi)
#pragma unroll
      for (int ni = 0; ni < 4; ++ni)
        acc[4 + mi][ni] = __builtin_amdgcn_mfma_f32_16x16x32_bf16(af2[mi], bf[ni],
                                                                  acc[4 + mi][ni], 0, 0, 0);
    __builtin_amdgcn_s_setprio(0);

    // ---- K-tile boundary. B(kt+1) drained by A_WRITE's implicit wait at
    // ph1 (kt<30); kt==30 has no A_WRITE -> explicit vmcnt(0) for B(31).
    // lgkmcnt(0): publish this tile's ds_writes before the barrier.
    if (kt == 30) asm volatile("s_waitcnt vmcnt(0)" ::: "memory");
    asm volatile("s_waitcnt lgkmcnt(0)" ::: "memory");
    __builtin_amdgcn_sched_barrier(0);
    __builtin_amdgcn_s_barrier();
  }

  // epilogue: C/D layout col=lane&15, row=quad*4+reg (m89-verified)
#pragma unroll
  for (int ni = 0; ni < 4; ++ni) {
    const int col = bn * 256 + wc * 64 + ni * 16 + row16;
    const float bb = base_b[col];
#pragma unroll
    for (int mi = 0; mi < 8; ++mi) {
      const int row = bm * 256 + wr * 128 + mi * 16 + quad * 4;
      float* po = out + (((size_t)b * 4096 + row) << 10) + col;
#pragma unroll
      for (int i2 = 0; i2 < 4; ++i2)
        po[(size_t)i2 << 10] = acc[mi][ni][i2] + bb;
    }
  }
#undef STAGE_B
#undef A_ISSUE
#undef A_WRITE
}

extern "C" void kernel_launch(void* const* d_in, const int* in_sizes, int n_in,
                              void* d_out, int out_size, void* d_ws, size_t ws_size,
                              hipStream_t stream) {
  const float* x  = (const float*)d_in[0];
  const float* mf = (const float*)d_in[1];
  const float* mm = (const float*)d_in[2];
  const float* ms = (const float*)d_in[3];
  const float* base_w = (const float*)d_in[4];
  const float* base_b = (const float*)d_in[5];
  const float* pd_w = (const float*)d_in[6];
  const float* pu_w = (const float*)d_in[7];
  // d_in[8..11] (gate net) are mathematically dead: mean(softmax_3) == 1/3.

  char* ws = (char*)d_ws;
  int* flags     = (int*)ws;                                   // 32 B
  ushort_t* W0   = (ushort_t*)(ws + 4096);                     // 2 MiB
  ushort_t* Weff = (ushort_t*)(ws + 4096 + (2u << 20));        // 16 MiB, cold

  prep<<<dim3(1024, 9), 128, 0, stream>>>(base_w, pu_w, pd_w, mf, mm, ms,
                                          W0, Weff, flags);
  gemm256<<<512, 512, 0, stream>>>(x, base_b, W0, Weff, flags, (float*)d_out);
}

// Round 7
// 339.009 us; speedup vs baseline: 1.0378x; 1.0378x over previous
//
#include <hip/hip_runtime.h>
#include <stdint.h>

// HOPELoRALayer — B=8, S=4096, D=1024, R_TOT=104. fp32 I/O; bf16 MFMA GEMM.
// Reductions:
//   gate_scale = mean(softmax over 3) == 1/3 exactly -> gate net dead code.
//   out = X @ (base_w + (1/3) pu@diag(1+mem)@pd)^T + base_b
// mem==0 (fresh state) -> batch-independent W0; general case kept via
// per-batch flag + Weff (computed only if mem[b]!=0).
//
// R10 = R9 fusion with A-load issue moved ONE FULL TILE ahead (T14 fix).
//   R9 stalled (~+2200cy/tile): A_ISSUE(kt+2) in ph0 and A_WRITE(kt+2) in
//   ph1 of the SAME tile put the implicit vmcnt wait ~600cy after issue vs
//   ~900cy HBM latency (fp32 x misses L2). Now ph1 of tile kt does:
//     STAGE_B(kt+2) -> A_WRITE(kt+2) -> A_ISSUE(kt+3)
//   A_WRITE consumes s0..s3 then A_ISSUE refills the SAME regs (WAR, zero
//   extra VGPR); issue-to-consume = one full tile (~3400cy >> HBM latency).
//   Implicit wait at A_WRITE drains exactly {B(kt+1), A(kt+2)}, leaves
//   {B(kt+2), A(kt+3)} in flight — counted-vmcnt invariant preserved.
//   Prologue queue: B0(2), A2(4), B1(2) outstanding -> vmcnt(6) drains B0.
// R7/R9 base: convert_x kernel deleted; A staged fp32->reg->cvt->swizzled
//   ds_write; B via global_load_lds with pre-swizzled source; ws 18 MB
//   (residual dropped 253->201 us: ~30 us kernel + ~15 us ws-memset).

typedef unsigned short ushort_t;
typedef unsigned short us8 __attribute__((ext_vector_type(8)));
typedef short short8 __attribute__((ext_vector_type(8)));
typedef float f32x4 __attribute__((ext_vector_type(4)));

__device__ __forceinline__ ushort_t f2b(float f) {  // RNE fp32->bf16
  union { float f; uint32_t i; } v; v.f = f;
  uint32_t lsb = (v.i >> 16) & 1u;
  v.i += 0x7fffu + lsb;
  return (ushort_t)(v.i >> 16);
}

__device__ __forceinline__ void async16(const void* g, void* l) {
  __builtin_amdgcn_global_load_lds(
      (const __attribute__((address_space(1))) void*)g,
      (__attribute__((address_space(3))) void*)l, 16, 0, 0);
}

// ---- merged prep: y==0 -> W0 row; y=1..8 -> flags[b] + Weff row if mem!=0 --
__global__ __launch_bounds__(128) void prep(const float* __restrict__ base_w,
                                            const float* __restrict__ pu_w,
                                            const float* __restrict__ pd_w,
                                            const float* __restrict__ mf,
                                            const float* __restrict__ mm,
                                            const float* __restrict__ ms,
                                            ushort_t* __restrict__ W0,
                                            ushort_t* __restrict__ Weff,
                                            int* __restrict__ flags) {
  const int o = blockIdx.x, y = blockIdx.y, t = threadIdx.x;
  __shared__ float spu[104];
  __shared__ int sflag;
  ushort_t* dst;

  if (y == 0) {
    if (t < 104) spu[t] = pu_w[o * 104 + t] * (1.0f / 3.0f);
    dst = W0 + o * 1024;
    __syncthreads();
  } else {
    const int b = y - 1;
    if (t == 0) sflag = 0;
    __syncthreads();
    float mv = 0.0f;
    if (t < 104) {
      mv = (t < 8) ? mf[b * 8 + t]
         : (t < 40) ? mm[b * 32 + (t - 8)]
                    : ms[b * 64 + (t - 40)];
      if (mv != 0.0f) sflag = 1;
      spu[t] = pu_w[o * 104 + t] * (1.0f + mv) * (1.0f / 3.0f);
    }
    __syncthreads();
    if (o == 0 && t == 0) flags[b] = sflag;
    if (!sflag) return;  // block-uniform
    dst = Weff + ((size_t)b << 20) + o * 1024;
  }

  const int d0 = t * 8;
  float acc[8];
  f32x4 b0 = *(const f32x4*)(base_w + o * 1024 + d0);
  f32x4 b1 = *(const f32x4*)(base_w + o * 1024 + d0 + 4);
#pragma unroll
  for (int j = 0; j < 4; j++) { acc[j] = b0[j]; acc[4 + j] = b1[j]; }
  for (int r = 0; r < 104; r++) {
    f32x4 p0 = *(const f32x4*)(pd_w + r * 1024 + d0);
    f32x4 p1 = *(const f32x4*)(pd_w + r * 1024 + d0 + 4);
    float s = spu[r];
#pragma unroll
    for (int j = 0; j < 4; j++) { acc[j] += s * p0[j]; acc[4 + j] += s * p1[j]; }
  }
  us8 ov;
#pragma unroll
  for (int j = 0; j < 8; j++) ov[j] = f2b(acc[j]);
  *(us8*)(dst + d0) = ov;
}

// ---- main GEMM: out[b, m, n] = sum_k x[b,m,k] * W[n,k] + base_b[n] --------
// 256x256 tile, BK=32. 8 waves (2M x 4N), per-wave 128x64 out = 8x4 frags of
// mfma_f32_16x16x32_bf16. Grid 512 blocks: b = flat&7 (batch==XCD).
// A read directly from fp32 x (reg-staged + in-kernel bf16 convert).
__global__ __launch_bounds__(512, 2) void gemm256(
    const float* __restrict__ x, const float* __restrict__ base_b,
    const ushort_t* __restrict__ W0, const ushort_t* __restrict__ Weff,
    const int* __restrict__ flags, float* __restrict__ out) {
  const int flat = blockIdx.x;
  const int b  = flat & 7;                 // batch == XCD
  const int i  = flat >> 3;                // 0..63
  const int bm = i >> 2;                   // 0..15 (M tile)
  const int bn = i & 3;                    // 0..3  (N tile)

  const ushort_t* W = flags[b] ? (Weff + ((size_t)b << 20)) : W0;

  // 4-deep ring: per buffer A[256][32] (16KiB) + B[256][32] (16KiB) = 32KiB
  __shared__ __align__(16) char lds[4 * 32768];  // 128 KiB

  const int t = threadIdx.x;
  const int w = t >> 6, l = t & 63;
  const int wr = w >> 2, wc = w & 3;       // wave -> (M half, N quarter)
  const int row16 = l & 15, quad = l >> 4;

  // ---- B staging (global_load_lds, source carries the inverse swizzle) ----
  const int srow = w * 16 + (l >> 2);
  const int scol = ((l & 3) ^ ((l >> 3) & 3)) * 8;     // bf16 units
  const ushort_t* gB = W + (((size_t)(bn * 256 + srow)) << 10) + scol;

  // ---- A staging (reg-staged fp32 -> cvt -> swizzled ds_write) ----
  // thread t covers LDS row ar = t>>1, fp32 cols ac..ac+15 (ac = (t&1)*16).
  const int ar = t >> 1;                               // 0..255
  const int ac = (t & 1) * 16;
  const float* gA = x + (((size_t)b * 4096 + bm * 256 + ar) << 10) + ac;
  const int fr_ = (ar >> 1) & 3;                       // row swizzle key
  const int ws0 = (((t & 1) * 2 + 0) ^ fr_) * 16;      // byte slots
  const int ws1 = (((t & 1) * 2 + 1) ^ fr_) * 16;

  // ---- ds_read addressing (applies the same XOR on the k-slot) ----
  const int qsw = (quad ^ ((row16 >> 1) & 3)) * 16;          // byte slot
  const int aoff = (wr * 128 + row16) * 64 + qsw;            // + mi*1024
  const int boff = 16384 + (wc * 64 + row16) * 64 + qsw;     // + ni*1024

#define STAGE_B(kt)                                                       \
  {                                                                       \
    const ushort_t* g_ = gB + (kt) * 32;                                  \
    char* d_ = lds + ((kt) & 3) * 32768 + 16384 + w * 1024;               \
    async16(g_, d_);                                                      \
    async16(g_ + (128 << 10), d_ + 8192);                                 \
  }
#define A_ISSUE(kt2)                                                      \
  {                                                                       \
    const float* p_ = gA + (kt2) * 32;                                    \
    s0 = *(const f32x4*)(p_);      s1 = *(const f32x4*)(p_ + 4);          \
    s2 = *(const f32x4*)(p_ + 8);  s3 = *(const f32x4*)(p_ + 12);         \
  }
#define A_WRITE(kt2)                                                      \
  {                                                                       \
    us8 o0, o1;                                                           \
    _Pragma("unroll")                                                     \
    for (int j_ = 0; j_ < 4; ++j_) {                                      \
      o0[j_] = f2b(s0[j_]); o0[4 + j_] = f2b(s1[j_]);                     \
      o1[j_] = f2b(s2[j_]); o1[4 + j_] = f2b(s3[j_]);                     \
    }                                                                     \
    char* d_ = lds + ((kt2) & 3) * 32768 + ar * 64;                       \
    *(us8*)(d_ + ws0) = o0;                                               \
    *(us8*)(d_ + ws1) = o1;                                               \
  }

  f32x4 acc[8][4] = {};
  f32x4 s0, s1, s2, s3;

  // prologue: A0,A1 cvt+written; A2 issued (stays in flight); B0,B1 issued.
  // Issue order -> queue at the wait: B0(2), A2(4), B1(2) = 8 outstanding
  // (A0/A1 drained by their A_WRITE implicit waits). vmcnt(6) drains
  // exactly B0; A2 + B1 stay in flight.
  A_ISSUE(0) A_WRITE(0)
  A_ISSUE(1) STAGE_B(0)
  A_WRITE(1) A_ISSUE(2)
  STAGE_B(1)
  asm volatile("s_waitcnt vmcnt(6) lgkmcnt(0)" ::: "memory");
  __builtin_amdgcn_s_barrier();

  for (int kt = 0; kt < 32; ++kt) {
    const char* cur = lds + (kt & 3) * 32768;

    // ---- phase 0: read af0..3 + bf0..3 | 16 MFMA ----
    short8 af[4], bf[4];
#pragma unroll
    for (int mi = 0; mi < 4; ++mi)
      af[mi] = *(const short8*)(cur + aoff + mi * 1024);
#pragma unroll
    for (int ni = 0; ni < 4; ++ni)
      bf[ni] = *(const short8*)(cur + boff + ni * 1024);
    __builtin_amdgcn_sched_barrier(0);   // pin reads before the barrier
    __builtin_amdgcn_s_barrier();
    __builtin_amdgcn_s_setprio(1);
#pragma unroll
    for (int mi = 0; mi < 4; ++mi)
#pragma unroll
      for (int ni = 0; ni < 4; ++ni)
        acc[mi][ni] = __builtin_amdgcn_mfma_f32_16x16x32_bf16(af[mi], bf[ni],
                                                              acc[mi][ni], 0, 0, 0);
    __builtin_amdgcn_s_setprio(0);

    // ---- phase 1: read af4..7 | STAGE_B(kt+2) -> A_WRITE(kt+2) ->
    //      A_ISSUE(kt+3) | 16 MFMA.
    //      A_WRITE's implicit wait targets A(kt+2) issued ONE TILE ago
    //      (landed) and drains B(kt+1) (needed at tile end anyway);
    //      B(kt+2) + A(kt+3) stay in flight.
    short8 af2[4];
#pragma unroll
    for (int mi = 0; mi < 4; ++mi)
      af2[mi] = *(const short8*)(cur + aoff + (4 + mi) * 1024);
    if (kt < 30) { STAGE_B(kt + 2) A_WRITE(kt + 2) }
    if (kt < 29) A_ISSUE(kt + 3)
    __builtin_amdgcn_sched_barrier(0);
    __builtin_amdgcn_s_barrier();
    __builtin_amdgcn_s_setprio(1);
#pragma unroll
    for (int mi = 0; mi < 4; ++mi)
#pragma unroll
      for (int ni = 0; ni < 4; ++ni)
        acc[4 + mi][ni] = __builtin_amdgcn_mfma_f32_16x16x32_bf16(af2[mi], bf[ni],
                                                                  acc[4 + mi][ni], 0, 0, 0);
    __builtin_amdgcn_s_setprio(0);

    // ---- K-tile boundary. B(kt+1) already drained by A_WRITE's implicit
    // wait (kt<30); kt==30 has no A_WRITE -> explicit vmcnt(0) for B(31).
    // lgkmcnt(0): publish this tile's ds_writes before the barrier.
    if (kt == 30) asm volatile("s_waitcnt vmcnt(0)" ::: "memory");
    asm volatile("s_waitcnt lgkmcnt(0)" ::: "memory");
    __builtin_amdgcn_sched_barrier(0);
    __builtin_amdgcn_s_barrier();
  }

  // epilogue: C/D layout col=lane&15, row=quad*4+reg (m89-verified)
#pragma unroll
  for (int ni = 0; ni < 4; ++ni) {
    const int col = bn * 256 + wc * 64 + ni * 16 + row16;
    const float bb = base_b[col];
#pragma unroll
    for (int mi = 0; mi < 8; ++mi) {
      const int row = bm * 256 + wr * 128 + mi * 16 + quad * 4;
      float* po = out + (((size_t)b * 4096 + row) << 10) + col;
#pragma unroll
      for (int i2 = 0; i2 < 4; ++i2)
        po[(size_t)i2 << 10] = acc[mi][ni][i2] + bb;
    }
  }
#undef STAGE_B
#undef A_ISSUE
#undef A_WRITE
}

extern "C" void kernel_launch(void* const* d_in, const int* in_sizes, int n_in,
                              void* d_out, int out_size, void* d_ws, size_t ws_size,
                              hipStream_t stream) {
  const float* x  = (const float*)d_in[0];
  const float* mf = (const float*)d_in[1];
  const float* mm = (const float*)d_in[2];
  const float* ms = (const float*)d_in[3];
  const float* base_w = (const float*)d_in[4];
  const float* base_b = (const float*)d_in[5];
  const float* pd_w = (const float*)d_in[6];
  const float* pu_w = (const float*)d_in[7];
  // d_in[8..11] (gate net) are mathematically dead: mean(softmax_3) == 1/3.

  char* ws = (char*)d_ws;
  int* flags     = (int*)ws;                                   // 32 B
  ushort_t* W0   = (ushort_t*)(ws + 4096);                     // 2 MiB
  ushort_t* Weff = (ushort_t*)(ws + 4096 + (2u << 20));        // 16 MiB, cold

  prep<<<dim3(1024, 9), 128, 0, stream>>>(base_w, pu_w, pd_w, mf, mm, ms,
                                          W0, Weff, flags);
  gemm256<<<512, 512, 0, stream>>>(x, base_b, W0, Weff, flags, (float*)d_out);
}

// Round 8
// 337.528 us; speedup vs baseline: 1.0423x; 1.0044x over previous
//
#include <hip/hip_runtime.h>
#include <stdint.h>

// HOPELoRALayer — B=8, S=4096, D=1024, R_TOT=104. fp32 I/O; bf16 MFMA GEMM.
// Reductions:
//   gate_scale = mean(softmax over 3) == 1/3 exactly -> gate net dead code.
//   out = X @ (base_w + (1/3) pu@diag(1+mem)@pd)^T + base_b
// mem==0 (fresh state) -> batch-independent W0; general case kept via
// per-batch flag + Weff (computed only if mem[b]!=0).
//
// R11 change: SINGLE barrier per K-tile (was 3). R6/R10 post-mortem: per-phase
// barriers lockstep all 8 waves -> LDS pipe and MFMA pipe alternate CU-wide
// (serial sum ~3400-5000 cy/tile vs ~1500 overlapped). The 4-deep ring makes
// the extra barriers redundant: tile kt reads buf[kt&3], writes buf[(kt+2)&3];
// with 1 barrier/tile max skew = 1 tile and fast-wave bufs {(kt+1)&3,(kt+3)&3}
// are disjoint from slow-wave {kt&3,(kt+2)&3} in all pairings. Publish deps:
// A ds_writes get 2 barriers (written kt, read kt+2); B glds drained by the
// NEXT tile's A_WRITE implicit vmcnt (B(kt+2) older than A(kt+3)) before that
// wave's end barrier, read one barrier later. NO explicit vmcnt in main loop.
// Per tile: {STAGE_B(kt+2), A_WRITE(kt+2), A_ISSUE(kt+3)} | sched_barrier |
// {12 ds_read ++ 32 MFMA compiler-interleaved} | lgkmcnt(0) | s_barrier.
// R7/R10 base: convert_x deleted (A: fp32 reg-stage + RNE cvt + swizzled
// ds_write, issue one full tile ahead); B: global_load_lds pre-swizzled src.

typedef unsigned short ushort_t;
typedef unsigned short us8 __attribute__((ext_vector_type(8)));
typedef short short8 __attribute__((ext_vector_type(8)));
typedef float f32x4 __attribute__((ext_vector_type(4)));

__device__ __forceinline__ ushort_t f2b(float f) {  // RNE fp32->bf16
  union { float f; uint32_t i; } v; v.f = f;
  uint32_t lsb = (v.i >> 16) & 1u;
  v.i += 0x7fffu + lsb;
  return (ushort_t)(v.i >> 16);
}

__device__ __forceinline__ void async16(const void* g, void* l) {
  __builtin_amdgcn_global_load_lds(
      (const __attribute__((address_space(1))) void*)g,
      (__attribute__((address_space(3))) void*)l, 16, 0, 0);
}

// ---- merged prep: y==0 -> W0 row; y=1..8 -> flags[b] + Weff row if mem!=0 --
__global__ __launch_bounds__(128) void prep(const float* __restrict__ base_w,
                                            const float* __restrict__ pu_w,
                                            const float* __restrict__ pd_w,
                                            const float* __restrict__ mf,
                                            const float* __restrict__ mm,
                                            const float* __restrict__ ms,
                                            ushort_t* __restrict__ W0,
                                            ushort_t* __restrict__ Weff,
                                            int* __restrict__ flags) {
  const int o = blockIdx.x, y = blockIdx.y, t = threadIdx.x;
  __shared__ float spu[104];
  __shared__ int sflag;
  ushort_t* dst;

  if (y == 0) {
    if (t < 104) spu[t] = pu_w[o * 104 + t] * (1.0f / 3.0f);
    dst = W0 + o * 1024;
    __syncthreads();
  } else {
    const int b = y - 1;
    if (t == 0) sflag = 0;
    __syncthreads();
    float mv = 0.0f;
    if (t < 104) {
      mv = (t < 8) ? mf[b * 8 + t]
         : (t < 40) ? mm[b * 32 + (t - 8)]
                    : ms[b * 64 + (t - 40)];
      if (mv != 0.0f) sflag = 1;
      spu[t] = pu_w[o * 104 + t] * (1.0f + mv) * (1.0f / 3.0f);
    }
    __syncthreads();
    if (o == 0 && t == 0) flags[b] = sflag;
    if (!sflag) return;  // block-uniform
    dst = Weff + ((size_t)b << 20) + o * 1024;
  }

  const int d0 = t * 8;
  float acc[8];
  f32x4 b0 = *(const f32x4*)(base_w + o * 1024 + d0);
  f32x4 b1 = *(const f32x4*)(base_w + o * 1024 + d0 + 4);
#pragma unroll
  for (int j = 0; j < 4; j++) { acc[j] = b0[j]; acc[4 + j] = b1[j]; }
  for (int r = 0; r < 104; r++) {
    f32x4 p0 = *(const f32x4*)(pd_w + r * 1024 + d0);
    f32x4 p1 = *(const f32x4*)(pd_w + r * 1024 + d0 + 4);
    float s = spu[r];
#pragma unroll
    for (int j = 0; j < 4; j++) { acc[j] += s * p0[j]; acc[4 + j] += s * p1[j]; }
  }
  us8 ov;
#pragma unroll
  for (int j = 0; j < 8; j++) ov[j] = f2b(acc[j]);
  *(us8*)(dst + d0) = ov;
}

// ---- main GEMM: out[b, m, n] = sum_k x[b,m,k] * W[n,k] + base_b[n] --------
// 256x256 tile, BK=32. 8 waves (2M x 4N), per-wave 128x64 out = 8x4 frags of
// mfma_f32_16x16x32_bf16. Grid 512 blocks: b = flat&7 (batch==XCD).
// A read directly from fp32 x (reg-staged + in-kernel bf16 convert).
__global__ __launch_bounds__(512, 2) void gemm256(
    const float* __restrict__ x, const float* __restrict__ base_b,
    const ushort_t* __restrict__ W0, const ushort_t* __restrict__ Weff,
    const int* __restrict__ flags, float* __restrict__ out) {
  const int flat = blockIdx.x;
  const int b  = flat & 7;                 // batch == XCD
  const int i  = flat >> 3;                // 0..63
  const int bm = i >> 2;                   // 0..15 (M tile)
  const int bn = i & 3;                    // 0..3  (N tile)

  const ushort_t* W = flags[b] ? (Weff + ((size_t)b << 20)) : W0;

  // 4-deep ring: per buffer A[256][32] (16KiB) + B[256][32] (16KiB) = 32KiB
  __shared__ __align__(16) char lds[4 * 32768];  // 128 KiB

  const int t = threadIdx.x;
  const int w = t >> 6, l = t & 63;
  const int wr = w >> 2, wc = w & 3;       // wave -> (M half, N quarter)
  const int row16 = l & 15, quad = l >> 4;

  // ---- B staging (global_load_lds, source carries the inverse swizzle) ----
  const int srow = w * 16 + (l >> 2);
  const int scol = ((l & 3) ^ ((l >> 3) & 3)) * 8;     // bf16 units
  const ushort_t* gB = W + (((size_t)(bn * 256 + srow)) << 10) + scol;

  // ---- A staging (reg-staged fp32 -> cvt -> swizzled ds_write) ----
  // thread t covers LDS row ar = t>>1, fp32 cols ac..ac+15 (ac = (t&1)*16).
  const int ar = t >> 1;                               // 0..255
  const int ac = (t & 1) * 16;
  const float* gA = x + (((size_t)b * 4096 + bm * 256 + ar) << 10) + ac;
  const int fr_ = (ar >> 1) & 3;                       // row swizzle key
  const int ws0 = (((t & 1) * 2 + 0) ^ fr_) * 16;      // byte slots
  const int ws1 = (((t & 1) * 2 + 1) ^ fr_) * 16;

  // ---- ds_read addressing (applies the same XOR on the k-slot) ----
  const int qsw = (quad ^ ((row16 >> 1) & 3)) * 16;          // byte slot
  const int aoff = (wr * 128 + row16) * 64 + qsw;            // + mi*1024
  const int boff = 16384 + (wc * 64 + row16) * 64 + qsw;     // + ni*1024

#define STAGE_B(kt)                                                       \
  {                                                                       \
    const ushort_t* g_ = gB + (kt) * 32;                                  \
    char* d_ = lds + ((kt) & 3) * 32768 + 16384 + w * 1024;               \
    async16(g_, d_);                                                      \
    async16(g_ + (128 << 10), d_ + 8192);                                 \
  }
#define A_ISSUE(kt2)                                                      \
  {                                                                       \
    const float* p_ = gA + (kt2) * 32;                                    \
    s0 = *(const f32x4*)(p_);      s1 = *(const f32x4*)(p_ + 4);          \
    s2 = *(const f32x4*)(p_ + 8);  s3 = *(const f32x4*)(p_ + 12);         \
  }
#define A_WRITE(kt2)                                                      \
  {                                                                       \
    us8 o0, o1;                                                           \
    _Pragma("unroll")                                                     \
    for (int j_ = 0; j_ < 4; ++j_) {                                      \
      o0[j_] = f2b(s0[j_]); o0[4 + j_] = f2b(s1[j_]);                     \
      o1[j_] = f2b(s2[j_]); o1[4 + j_] = f2b(s3[j_]);                     \
    }                                                                     \
    char* d_ = lds + ((kt2) & 3) * 32768 + ar * 64;                       \
    *(us8*)(d_ + ws0) = o0;                                               \
    *(us8*)(d_ + ws1) = o1;                                               \
  }

  f32x4 acc[8][4] = {};
  f32x4 s0, s1, s2, s3;

  // prologue: A0,A1 cvt+written; A2 issued (in flight); B0,B1 issued.
  // VM queue at the wait: [B0:2, A2:4, B1:2] (A0/A1 reg-loads drained by
  // their A_WRITE implicit waits) -> vmcnt(6) drains exactly B0.
  A_ISSUE(0) A_WRITE(0)
  A_ISSUE(1) STAGE_B(0)
  A_WRITE(1) A_ISSUE(2)
  STAGE_B(1)
  asm volatile("s_waitcnt vmcnt(6) lgkmcnt(0)" ::: "memory");
  __builtin_amdgcn_s_barrier();

  for (int kt = 0; kt < 32; ++kt) {
    const char* cur = lds + (kt & 3) * 32768;

    // ---- staging group (pinned before the compute region) ----
    // A_WRITE(kt+2)'s implicit vmcnt waits for A(kt+2) (issued one full tile
    // ago) and, being counted, drains B(kt+1) (older in queue) — the buffer
    // published at this tile's end barrier. B(kt+2)+A(kt+3) stay in flight.
    if (kt < 30) { STAGE_B(kt + 2) A_WRITE(kt + 2) }
    if (kt < 29) A_ISSUE(kt + 3)
    __builtin_amdgcn_sched_barrier(0);

    // ---- compute region: 12 ds_read + 32 MFMA, compiler-interleaved ----
    __builtin_amdgcn_s_setprio(1);
    short8 af[4], bf[4], af2[4];
#pragma unroll
    for (int mi = 0; mi < 4; ++mi)
      af[mi] = *(const short8*)(cur + aoff + mi * 1024);
#pragma unroll
    for (int ni = 0; ni < 4; ++ni)
      bf[ni] = *(const short8*)(cur + boff + ni * 1024);
#pragma unroll
    for (int mi = 0; mi < 4; ++mi)
      af2[mi] = *(const short8*)(cur + aoff + (4 + mi) * 1024);
#pragma unroll
    for (int mi = 0; mi < 4; ++mi)
#pragma unroll
      for (int ni = 0; ni < 4; ++ni)
        acc[mi][ni] = __builtin_amdgcn_mfma_f32_16x16x32_bf16(af[mi], bf[ni],
                                                              acc[mi][ni], 0, 0, 0);
#pragma unroll
    for (int mi = 0; mi < 4; ++mi)
#pragma unroll
      for (int ni = 0; ni < 4; ++ni)
        acc[4 + mi][ni] = __builtin_amdgcn_mfma_f32_16x16x32_bf16(af2[mi], bf[ni],
                                                                  acc[4 + mi][ni], 0, 0, 0);
    __builtin_amdgcn_s_setprio(0);

    // ---- K-tile end: kt==30 has no A_WRITE -> explicit drain of B(31).
    // lgkmcnt(0) publishes this tile's ds_writes; single barrier per tile.
    if (kt == 30) asm volatile("s_waitcnt vmcnt(0)" ::: "memory");
    asm volatile("s_waitcnt lgkmcnt(0)" ::: "memory");
    __builtin_amdgcn_sched_barrier(0);
    __builtin_amdgcn_s_barrier();
  }

  // epilogue: C/D layout col=lane&15, row=quad*4+reg (m89-verified)
#pragma unroll
  for (int ni = 0; ni < 4; ++ni) {
    const int col = bn * 256 + wc * 64 + ni * 16 + row16;
    const float bb = base_b[col];
#pragma unroll
    for (int mi = 0; mi < 8; ++mi) {
      const int row = bm * 256 + wr * 128 + mi * 16 + quad * 4;
      float* po = out + (((size_t)b * 4096 + row) << 10) + col;
#pragma unroll
      for (int i2 = 0; i2 < 4; ++i2)
        po[(size_t)i2 << 10] = acc[mi][ni][i2] + bb;
    }
  }
#undef STAGE_B
#undef A_ISSUE
#undef A_WRITE
}

extern "C" void kernel_launch(void* const* d_in, const int* in_sizes, int n_in,
                              void* d_out, int out_size, void* d_ws, size_t ws_size,
                              hipStream_t stream) {
  const float* x  = (const float*)d_in[0];
  const float* mf = (const float*)d_in[1];
  const float* mm = (const float*)d_in[2];
  const float* ms = (const float*)d_in[3];
  const float* base_w = (const float*)d_in[4];
  const float* base_b = (const float*)d_in[5];
  const float* pd_w = (const float*)d_in[6];
  const float* pu_w = (const float*)d_in[7];
  // d_in[8..11] (gate net) are mathematically dead: mean(softmax_3) == 1/3.

  char* ws = (char*)d_ws;
  int* flags     = (int*)ws;                                   // 32 B
  ushort_t* W0   = (ushort_t*)(ws + 4096);                     // 2 MiB
  ushort_t* Weff = (ushort_t*)(ws + 4096 + (2u << 20));        // 16 MiB, cold

  prep<<<dim3(1024, 9), 128, 0, stream>>>(base_w, pu_w, pd_w, mf, mm, ms,
                                          W0, Weff, flags);
  gemm256<<<512, 512, 0, stream>>>(x, base_b, W0, Weff, flags, (float*)d_out);
}